// Round 4
// baseline (22792.592 us; speedup 1.0000x reference)
//
#include <hip/hip_runtime.h>
#include <math.h>

// ---------------- constants ----------------
#define T_STEPS 8192
#define IN_DIM  1024
#define HD      1024
#define ZD      4096          // 4 gates * HD, order [i, j, f, o]
#define G2      256           // phase-2 workgroups (each owns 4 h-cols x 4 gates)
#define B2      128           // phase-2 block size (2 waves)

typedef short  short8 __attribute__((ext_vector_type(8)));
typedef float  f32x4  __attribute__((ext_vector_type(4)));

__device__ __forceinline__ unsigned short f2bf(float f) {
    unsigned u = __float_as_uint(f);
    unsigned r = (u + 0x7fffu + ((u >> 16) & 1u)) >> 16;
    return (unsigned short)r;
}

// ---------------- phase 0: pack Wx (rows 0..1023 of W) into bf16 tile layout ----
// Wt[tile_n][tile_k][col 0..127][kk 0..31], elem = Wx[tile_k*32+kk][tile_n*128+col]
__global__ void wt_pack(const float* __restrict__ W, unsigned short* __restrict__ Wt) {
    int idx = blockIdx.x * 256 + threadIdx.x;      // 0 .. 4M-1
    int k = idx >> 12;                             // 0..1023
    int c = idx & 4095;                            // 0..4095
    float v = W[(size_t)k * ZD + c];               // coalesced read
    int tn = c >> 7, col = c & 127;
    int tk = k >> 5, kk = k & 31;
    Wt[(((size_t)(tn * 32 + tk) * 128 + col) << 5) + kk] = f2bf(v);
}

// ---------------- phase 1: ZX = x @ Wx + b (bf16 MFMA, fp32 accum) --------------
// Output layout is PERMUTED for phase 2: for z-column cg (0..4095) with
// gate = cg>>10, cc = cg&1023: pcol = (cc>>2)*16 + gate*4 + (cc&3).
// -> each phase-2 WG's 16 z values are one contiguous 64B line.
#define BM 128
#define BN 128
#define BKK 32
#define LDA 40    // padded LDS stride (bf16 elems): 80B = 20 banks, 16B-aligned rows

__global__ __launch_bounds__(256) void zx_gemm(const float* __restrict__ x,
                                               const unsigned short* __restrict__ Wt,
                                               const float* __restrict__ b,
                                               float* __restrict__ zx) {
    __shared__ unsigned short As[128 * LDA];
    __shared__ unsigned short Bs[128 * LDA];
    const int tid  = threadIdx.x;
    const int wave = tid >> 6, lane = tid & 63;
    const int wr = wave & 1, wc = wave >> 1;
    const int m0 = blockIdx.y * BM, n0 = blockIdx.x * BN;
    const int quad = lane >> 4, l16 = lane & 15;

    f32x4 acc[4][4] = {};
    float bias[4];
#pragma unroll
    for (int j = 0; j < 4; ++j) bias[j] = b[n0 + wc * 64 + j * 16 + l16];

    for (int it = 0; it < IN_DIM / BKK; ++it) {
        const int k0 = it * BKK;
        // stage A: x[m0..+127][k0..+31] fp32 -> bf16 LDS
        {
            int r  = tid >> 3;          // 0..31
            int k4 = (tid & 7) * 4;
#pragma unroll
            for (int p = 0; p < 4; ++p) {
                int rr = r + p * 32;
                float4 v = *(const float4*)&x[(size_t)(m0 + rr) * IN_DIM + k0 + k4];
                unsigned p0 = (unsigned)f2bf(v.x) | ((unsigned)f2bf(v.y) << 16);
                unsigned p1 = (unsigned)f2bf(v.z) | ((unsigned)f2bf(v.w) << 16);
                *(uint2*)&As[rr * LDA + k4] = make_uint2(p0, p1);
            }
        }
        // stage B: pre-packed contiguous 8KB tile -> LDS (pad stride 40)
        {
            const uint4* src = (const uint4*)(Wt + ((size_t)(n0 >> 7) * 32 + it) * 4096);
#pragma unroll
            for (int p = 0; p < 2; ++p) {
                int id = tid * 2 + p;           // 0..511
                int col = id >> 2, kp = id & 3;
                uint4 v = src[id];
                *(uint4*)&Bs[col * LDA + kp * 8] = v;
            }
        }
        __syncthreads();
        short8 af[4], bfr[4];
#pragma unroll
        for (int i = 0; i < 4; ++i)
            af[i] = *(const short8*)&As[(wr * 64 + i * 16 + l16) * LDA + quad * 8];
#pragma unroll
        for (int j = 0; j < 4; ++j)
            bfr[j] = *(const short8*)&Bs[(wc * 64 + j * 16 + l16) * LDA + quad * 8];
#pragma unroll
        for (int i = 0; i < 4; ++i)
#pragma unroll
            for (int j = 0; j < 4; ++j)
                acc[i][j] = __builtin_amdgcn_mfma_f32_16x16x32_bf16(af[i], bfr[j], acc[i][j], 0, 0, 0);
        __syncthreads();
    }
    // epilogue: D row = quad*4 + reg, col = l16; store to permuted z layout
#pragma unroll
    for (int i = 0; i < 4; ++i) {
        int row = m0 + wr * 64 + i * 16 + quad * 4;
#pragma unroll
        for (int j = 0; j < 4; ++j) {
            int cg   = n0 + wc * 64 + j * 16 + l16;
            int gate = cg >> 10, cc = cg & 1023;
            int pcol = ((cc >> 2) << 4) + (gate << 2) + (cc & 3);
#pragma unroll
            for (int r = 0; r < 4; ++r)
                zx[(size_t)(row + r) * ZD + pcol] = acc[i][j][r] + bias[j];
        }
    }
}

// ---------------- fast activations (critical path) ----------------
__device__ __forceinline__ float sigmoid_fast(float x) {
    float e = __expf(-x);
    return __builtin_amdgcn_rcpf(1.f + e);
}
__device__ __forceinline__ float tanh_fast(float x) {
    // 1 - 2/(e^{2x}+1); e=inf -> 1, e=0 -> -1 (no NaN at extremes)
    float e = __expf(2.f * x);
    return 1.f - 2.f * __builtin_amdgcn_rcpf(e + 1.f);
}

// ---------------- phase 2: sequential recurrence (cooperative, 256 WGs) ---------
// WG g owns h-cols [4g,4g+4); local z-col zc = gate*4+col (0..15), global
// z-col = g*4+col+1024*gate. Thread t: zc = t&15, seg = t>>4. 128 w regs/thread.
// lds_h padded: seg stride 132 floats -> bank base 4*seg -> the 4 seg-groups in a
// wave hit 4 distinct bank quads (conflict-free b128 broadcast).
// h exchange: tagged 8B packets {step+1, fp32} in a parity double-buffer.
__global__ __launch_bounds__(B2, 1) void lstm_seq(const float* __restrict__ W,
                                                  const float* __restrict__ zx,
                                                  float* __restrict__ out,
                                                  unsigned long long* htag) {
    __shared__ float lds_h[8 * 132];   // 4.2 KB, padded
    __shared__ float zlds[16];         // wave-1 partials
    const int g    = blockIdx.x;
    const int t    = threadIdx.x;      // 0..127
    const int zc   = t & 15;
    const int seg  = t >> 4;           // 0..7
    const int gate = zc >> 2;          // 0..3 [i,j,f,o]
    const int col  = zc & 3;           // 0..3 (h-col within WG)
    const int zcol = g * 4 + col + (gate << 10);

    // Wh slice -> 128 regs (Wh rows are W rows 1024..2047), natural order
    float w[128];
#pragma unroll
    for (int j = 0; j < 128; ++j)
        w[j] = W[(size_t)(IN_DIM + (seg << 7) + j) * ZD + zcol];

    // zx for step 0, carried in registers by wave-0 lanes 0..15
    float zcur = 0.f;
    if (t < 16) zcur = zx[g * 16 + t];

    float c_state = 0.f;

    for (int s = 0; s < T_STEPS; ++s) {
        // ---- A: acquire h_s — issue all 8 tagged loads, then check ----
        const unsigned long long* src = htag + ((s & 1) << 10);
        unsigned long long v[8];
#pragma unroll
        for (int i = 0; i < 8; ++i)
            v[i] = __hip_atomic_load(&src[(i << 7) + t], __ATOMIC_RELAXED,
                                     __HIP_MEMORY_SCOPE_AGENT);
        while (true) {
            bool ok = true;
#pragma unroll
            for (int i = 0; i < 8; ++i) ok &= ((unsigned)(v[i] >> 32) == (unsigned)s);
            if (ok) break;
#pragma unroll
            for (int i = 0; i < 8; ++i)
                if ((unsigned)(v[i] >> 32) != (unsigned)s)
                    v[i] = __hip_atomic_load(&src[(i << 7) + t], __ATOMIC_RELAXED,
                                             __HIP_MEMORY_SCOPE_AGENT);
        }
        // prefetch zx row s+1 (wave 0 lanes 0..15; latency hidden behind S1+FMA)
        float znext = 0.f;
        if (t < 16 && s + 1 < T_STEPS)
            znext = zx[(size_t)(s + 1) * ZD + g * 16 + t];
        // stage h into padded LDS: idx = i*128+t -> seg block i at stride 132
#pragma unroll
        for (int i = 0; i < 8; ++i)
            lds_h[i * 132 + t] = __uint_as_float((unsigned)v[i]);
        __syncthreads();                               // S1: lds_h ready
        // ---- B: 128 FMAs, b128 broadcast per 16-lane group, conflict-free ----
        float a0 = 0.f, a1 = 0.f, a2 = 0.f, a3 = 0.f;
        const float4* hp = (const float4*)&lds_h[seg * 132];
#pragma unroll
        for (int j4 = 0; j4 < 32; ++j4) {
            float4 hv = hp[j4];
            a0 = fmaf(w[j4 * 4 + 0], hv.x, a0);
            a1 = fmaf(w[j4 * 4 + 1], hv.y, a1);
            a2 = fmaf(w[j4 * 4 + 2], hv.z, a2);
            a3 = fmaf(w[j4 * 4 + 3], hv.w, a3);
        }
        float p = (a0 + a1) + (a2 + a3);
        // reduce the wave's 4 seg-groups (lanes zc, zc+16, zc+32, zc+48)
        p += __shfl_xor(p, 16);
        p += __shfl_xor(p, 32);
        if (t >= 64 && t < 80)                         // wave-1 total per zc
            zlds[t - 64] = p;
        __syncthreads();                               // S2: zlds ready
        // ---- C: wave 0 combines, gates, publishes ----
        if (t < 16) {
            float z = p + zlds[t] + zcur;
            zcur = znext;
            // gates for col c live at lanes c, 4+c, 8+c, 12+c
            float zi = __shfl(z, t & 3);
            float zj = __shfl(z, (t & 3) + 4);
            float zf = __shfl(z, (t & 3) + 8);
            float zo = __shfl(z, (t & 3) + 12);
            if (t < 4) {
                float fg = sigmoid_fast(zf + 1.0f);    // FORGET_BIAS = 1.0
                float ig = sigmoid_fast(zi);
                float og = sigmoid_fast(zo);
                c_state = c_state * fg + ig * tanh_fast(zj);
                float h = tanh_fast(c_state) * og;
                unsigned long long pv =
                    ((unsigned long long)(unsigned)(s + 1) << 32) |
                    (unsigned long long)__float_as_uint(h);
                __hip_atomic_store(&htag[(((s + 1) & 1) << 10) + g * 4 + t], pv,
                                   __ATOMIC_RELAXED, __HIP_MEMORY_SCOPE_AGENT);
                out[(size_t)s * HD + g * 4 + t] = h;   // off critical path
            }
        }
        // no 3rd sync needed: next-iter lds_h writes happen only after this WG's
        // waves all passed S2 (spin + S1 of next iter order them).
    }
}

// ---------------- launch ----------------
extern "C" void kernel_launch(void* const* d_in, const int* in_sizes, int n_in,
                              void* d_out, int out_size, void* d_ws, size_t ws_size,
                              hipStream_t stream) {
    const float* x = (const float*)d_in[0];   // [8192,1024]
    const float* W = (const float*)d_in[1];   // [2048,4096]
    const float* b = (const float*)d_in[2];   // [4096]
    float* out = (float*)d_out;               // [8192,1024]

    char* ws = (char*)d_ws;
    // ws layout: zx 128MB | htag 16KB | Wt 8MB
    float*              zxp  = (float*)ws;
    const size_t        ZXB  = (size_t)T_STEPS * ZD * sizeof(float);   // 134217728
    unsigned long long* htag = (unsigned long long*)(ws + ZXB);
    unsigned short*     Wt   = (unsigned short*)(ws + ZXB + 16384);

    // h_0 = 0 with tag 0 in both parity slots (ws is poisoned 0xAA each call)
    hipMemsetAsync(htag, 0, 16384, stream);

    // phase 0: pack Wx -> bf16 tiles
    wt_pack<<<dim3((IN_DIM * ZD) / 256), dim3(256), 0, stream>>>(W, Wt);

    // phase 1: ZX = x @ Wx + b (permuted output layout)
    zx_gemm<<<dim3(ZD / BN, T_STEPS / BM), dim3(256), 0, stream>>>(x, Wt, b, zxp);

    // phase 2: sequential recurrence (cooperative for guaranteed co-residency)
    void* args[] = { (void*)&W, (void*)&zxp, (void*)&out, (void*)&htag };
    hipLaunchCooperativeKernel((void*)lstm_seq, dim3(G2), dim3(B2), args, 0, stream);
}